// Round 1
// baseline (1372.992 us; speedup 1.0000x reference)
//
#include <hip/hip_runtime.h>
#include <math.h>

#define BB 4
#define SS 1024
#define DD 1024
#define NH 16
#define HD 64

// ---------------------------------------------------------------------------
// Y[M,1024] = X[M,1024] @ W[1024,1024] + bias ; optionally store head-split
// as Y[(b*NH+h), s, d] with h=col/64, d=col%64, b=row/1024, s=row%1024.
// 64x64 output tile per 256-thread block, BK=16, 4x4 per-thread microtile.
// ---------------------------------------------------------------------------
template <bool HEAD_SPLIT>
__global__ void proj_gemm(const float* __restrict__ X, const float* __restrict__ W,
                          const float* __restrict__ bias, float* __restrict__ Y) {
    __shared__ float As[16][65];  // [k][m]
    __shared__ float Bs[16][65];  // [k][n]
    const int tid  = threadIdx.x;
    const int row0 = blockIdx.y * 64;
    const int col0 = blockIdx.x * 64;
    const int ty = tid >> 4, tx = tid & 15;

    float acc[4][4] = {};

    for (int k0 = 0; k0 < 1024; k0 += 16) {
        // X tile: 64 rows x 16 k
        {
            const int k = tid & 15, m = tid >> 4;  // m in 0..15
#pragma unroll
            for (int i = 0; i < 4; i++)
                As[k][m + 16 * i] = X[(size_t)(row0 + m + 16 * i) * 1024 + k0 + k];
        }
        // W tile: 16 k x 64 cols (coalesced: 64 consecutive floats per wave)
        {
            const int n = tid & 63, kk = tid >> 6;  // kk in 0..3
#pragma unroll
            for (int i = 0; i < 4; i++)
                Bs[kk + 4 * i][n] = W[(size_t)(k0 + kk + 4 * i) * 1024 + col0 + n];
        }
        __syncthreads();
#pragma unroll
        for (int k = 0; k < 16; k++) {
            float a[4], b[4];
#pragma unroll
            for (int i = 0; i < 4; i++) a[i] = As[k][ty * 4 + i];
#pragma unroll
            for (int j = 0; j < 4; j++) b[j] = Bs[k][tx * 4 + j];
#pragma unroll
            for (int i = 0; i < 4; i++)
#pragma unroll
                for (int j = 0; j < 4; j++) acc[i][j] += a[i] * b[j];
        }
        __syncthreads();
    }

#pragma unroll
    for (int i = 0; i < 4; i++) {
        const int r = row0 + ty * 4 + i;
#pragma unroll
        for (int j = 0; j < 4; j++) {
            const int c = col0 + tx * 4 + j;
            const float v = acc[i][j] + bias[c];
            if (HEAD_SPLIT) {
                const int b = r >> 10, s = r & 1023, h = c >> 6, d = c & 63;
                Y[((size_t)(b * NH + h) * SS + s) * HD + d] = v;
            } else {
                Y[(size_t)r * 1024 + c] = v;
            }
        }
    }
}

// ---------------------------------------------------------------------------
// Per (b,h): P[s,t] = (1/8) * sum_d Q[s,d]*K[t,d].  Q,K are [BH, S, 64].
// 64x64 tile, full K-dim (64) staged in LDS.
// ---------------------------------------------------------------------------
__global__ void scores_kernel(const float* __restrict__ Q, const float* __restrict__ K,
                              float* __restrict__ P) {
    __shared__ float Qs[64][65];
    __shared__ float Ks[64][65];
    const int bh = blockIdx.z;
    const int s0 = blockIdx.y * 64;
    const int t0 = blockIdx.x * 64;
    const float* q = Q + (size_t)bh * SS * HD;
    const float* k = K + (size_t)bh * SS * HD;
    const int tid = threadIdx.x;
    {
        const int d = tid & 63, r = tid >> 6;  // r in 0..3
#pragma unroll
        for (int i = 0; i < 16; i++) {
            Qs[r + 4 * i][d] = q[(size_t)(s0 + r + 4 * i) * HD + d];
            Ks[r + 4 * i][d] = k[(size_t)(t0 + r + 4 * i) * HD + d];
        }
    }
    __syncthreads();

    const int ty = tid >> 4, tx = tid & 15;
    float acc[4][4] = {};
#pragma unroll 8
    for (int kd = 0; kd < 64; kd++) {
        float a[4], b[4];
#pragma unroll
        for (int i = 0; i < 4; i++) a[i] = Qs[ty * 4 + i][kd];
#pragma unroll
        for (int j = 0; j < 4; j++) b[j] = Ks[tx * 4 + j][kd];
#pragma unroll
        for (int i = 0; i < 4; i++)
#pragma unroll
            for (int j = 0; j < 4; j++) acc[i][j] += a[i] * b[j];
    }

    const float scale = 0.125f;  // 1/sqrt(64)
#pragma unroll
    for (int i = 0; i < 4; i++) {
        const size_t srow = (size_t)bh * SS + (s0 + ty * 4 + i);
#pragma unroll
        for (int j = 0; j < 4; j++)
            P[srow * SS + (t0 + tx * 4 + j)] = acc[i][j] * scale;
    }
}

// ---------------------------------------------------------------------------
// In-place row softmax: 65536 rows of 1024 floats; one 256-thread block/row.
// ---------------------------------------------------------------------------
__global__ void softmax_kernel(float* __restrict__ P) {
    const size_t row = blockIdx.x;
    float* p = P + row * (size_t)SS;
    const int tid = threadIdx.x;

    float4 v = reinterpret_cast<float4*>(p)[tid];
    float m = fmaxf(fmaxf(v.x, v.y), fmaxf(v.z, v.w));
#pragma unroll
    for (int off = 32; off > 0; off >>= 1) m = fmaxf(m, __shfl_down(m, off));
    __shared__ float redm[4];
    if ((tid & 63) == 0) redm[tid >> 6] = m;
    __syncthreads();
    m = fmaxf(fmaxf(redm[0], redm[1]), fmaxf(redm[2], redm[3]));

    float4 e;
    e.x = __expf(v.x - m);
    e.y = __expf(v.y - m);
    e.z = __expf(v.z - m);
    e.w = __expf(v.w - m);
    float s = e.x + e.y + e.z + e.w;
#pragma unroll
    for (int off = 32; off > 0; off >>= 1) s += __shfl_down(s, off);
    __shared__ float reds[4];
    if ((tid & 63) == 0) reds[tid >> 6] = s;
    __syncthreads();
    s = reds[0] + reds[1] + reds[2] + reds[3];

    const float inv = 1.0f / s;
    e.x *= inv; e.y *= inv; e.z *= inv; e.w *= inv;
    reinterpret_cast<float4*>(p)[tid] = e;
}

// ---------------------------------------------------------------------------
// Per (b,h): ctx[s,d] = sum_t P[s,t] * V[t,d]; store as C[b, s, h*64+d].
// 64(row) x 64(full width) tile, BK=16.
// ---------------------------------------------------------------------------
__global__ void ctx_kernel(const float* __restrict__ P, const float* __restrict__ V,
                           float* __restrict__ C) {
    __shared__ float Ps[64][17];  // [s][t]
    __shared__ float Vs[16][65];  // [t][d]
    const int bh = blockIdx.z;
    const int s0 = blockIdx.y * 64;
    const float* p = P + (size_t)bh * SS * SS;
    const float* v = V + (size_t)bh * SS * HD;
    const int tid = threadIdx.x;
    const int ty = tid >> 4, tx = tid & 15;

    float acc[4][4] = {};

    for (int t0 = 0; t0 < 1024; t0 += 16) {
        {
            const int tt = tid & 15, sr = tid >> 4;  // sr in 0..15
#pragma unroll
            for (int i = 0; i < 4; i++)
                Ps[sr + 16 * i][tt] = p[(size_t)(s0 + sr + 16 * i) * SS + t0 + tt];
        }
        {
            const int d = tid & 63, tr = tid >> 6;  // tr in 0..3
#pragma unroll
            for (int i = 0; i < 4; i++)
                Vs[tr + 4 * i][d] = v[(size_t)(t0 + tr + 4 * i) * HD + d];
        }
        __syncthreads();
#pragma unroll
        for (int k = 0; k < 16; k++) {
            float a[4], b[4];
#pragma unroll
            for (int i = 0; i < 4; i++) a[i] = Ps[ty * 4 + i][k];
#pragma unroll
            for (int j = 0; j < 4; j++) b[j] = Vs[k][tx * 4 + j];
#pragma unroll
            for (int i = 0; i < 4; i++)
#pragma unroll
                for (int j = 0; j < 4; j++) acc[i][j] += a[i] * b[j];
        }
        __syncthreads();
    }

    const int b = bh >> 4, h = bh & 15;
#pragma unroll
    for (int i = 0; i < 4; i++) {
        const size_t r = (size_t)b * SS + (s0 + ty * 4 + i);
#pragma unroll
        for (int j = 0; j < 4; j++)
            C[r * DD + h * HD + tx * 4 + j] = acc[i][j];
    }
}

// ---------------------------------------------------------------------------
extern "C" void kernel_launch(void* const* d_in, const int* in_sizes, int n_in,
                              void* d_out, int out_size, void* d_ws, size_t ws_size,
                              hipStream_t stream) {
    const float* x  = (const float*)d_in[0];
    const float* Wq = (const float*)d_in[1];
    const float* bq = (const float*)d_in[2];
    const float* Wk = (const float*)d_in[3];
    const float* bk = (const float*)d_in[4];
    const float* Wv = (const float*)d_in[5];
    const float* bv = (const float*)d_in[6];
    const float* Wo = (const float*)d_in[7];
    const float* bo = (const float*)d_in[8];

    float* out   = (float*)d_out;                       // [B,S,D] = 4,194,304 floats
    float* probs = out + (size_t)BB * SS * DD;          // [B,H,S,S] = 67,108,864 floats

    const size_t qkv_elems = (size_t)BB * NH * SS * HD; // 4,194,304
    float* q   = (float*)d_ws;
    float* k   = q + qkv_elems;
    float* v   = k + qkv_elems;
    float* ctx = v + qkv_elems;                          // [B,S,D]

    const dim3 blk(256);

    // Projections: grid (N/64, M/64) = (16, 64)
    proj_gemm<true><<<dim3(16, 64), blk, 0, stream>>>(x, Wq, bq, q);
    proj_gemm<true><<<dim3(16, 64), blk, 0, stream>>>(x, Wk, bk, k);
    proj_gemm<true><<<dim3(16, 64), blk, 0, stream>>>(x, Wv, bv, v);

    // Scores (pre-softmax) straight into probs region
    scores_kernel<<<dim3(16, 16, BB * NH), blk, 0, stream>>>(q, k, probs);

    // Row softmax in place
    softmax_kernel<<<dim3(BB * NH * SS), blk, 0, stream>>>(probs);

    // ctx = P @ V, stored [B,S,D]
    ctx_kernel<<<dim3(1, 16, BB * NH), blk, 0, stream>>>(probs, v, ctx);

    // out = ctx @ Wo + bo
    proj_gemm<false><<<dim3(16, 64), blk, 0, stream>>>(ctx, Wo, bo, out);
}

// Round 2
// 467.722 us; speedup vs baseline: 2.9355x; 2.9355x over previous
//
#include <hip/hip_runtime.h>
#include <math.h>

typedef unsigned short u16;
typedef __attribute__((ext_vector_type(8))) short short8;
typedef __attribute__((ext_vector_type(4))) float f32x4;

#define BB 4
#define SS 1024
#define DD 1024
#define NH 16
#define HD 64
#define BH 64  // BB*NH

// fp32 -> bf16 round-to-nearest-even
__device__ __forceinline__ u16 f2bf(float f) {
    union { float f; unsigned u; } v;
    v.f = f;
    unsigned r = v.u + 0x7fffu + ((v.u >> 16) & 1u);
    return (u16)(r >> 16);
}

// ---------------------------------------------------------------------------
// Elementwise cast fp32 -> bf16, 4 elems/thread.
// ---------------------------------------------------------------------------
__global__ void cast_bf16(const float* __restrict__ X, u16* __restrict__ Y) {
    const int i = blockIdx.x * blockDim.x + threadIdx.x;
    const float4 v = reinterpret_cast<const float4*>(X)[i];
    ushort4 o;
    o.x = f2bf(v.x); o.y = f2bf(v.y); o.z = f2bf(v.z); o.w = f2bf(v.w);
    reinterpret_cast<ushort4*>(Y)[i] = o;
}

// ---------------------------------------------------------------------------
// Transpose-cast all 4 weight matrices: W[k][n] fp32 -> Wt[n][k] bf16.
// 64x64 tiles, LDS staging, blockIdx.z selects the matrix.
// ---------------------------------------------------------------------------
__global__ void transpose_cast_w(const float* __restrict__ W0, const float* __restrict__ W1,
                                 const float* __restrict__ W2, const float* __restrict__ W3,
                                 u16* __restrict__ O0, u16* __restrict__ O1,
                                 u16* __restrict__ O2, u16* __restrict__ O3) {
    __shared__ float T[64][65];
    const int z = blockIdx.z;
    const float* W = (z == 0) ? W0 : (z == 1) ? W1 : (z == 2) ? W2 : W3;
    u16* O = (z == 0) ? O0 : (z == 1) ? O1 : (z == 2) ? O2 : O3;
    const int k0 = blockIdx.x * 64, n0 = blockIdx.y * 64;
    const int x = threadIdx.x & 63, yq = threadIdx.x >> 6;
#pragma unroll
    for (int r = 0; r < 16; r++) {
        const int row = yq * 16 + r;
        T[row][x] = W[(size_t)(k0 + row) * 1024 + n0 + x];
    }
    __syncthreads();
#pragma unroll
    for (int r = 0; r < 16; r++) {
        const int row = yq * 16 + r;
        O[(size_t)(n0 + row) * 1024 + k0 + x] = f2bf(T[x][row]);
    }
}

// ---------------------------------------------------------------------------
// Transpose v (bf16): [bh][t][64] -> vT [bh][d][1024]
// ---------------------------------------------------------------------------
__global__ void transpose_v(const u16* __restrict__ V, u16* __restrict__ VT) {
    __shared__ u16 T[64][66];
    const int t0 = blockIdx.x * 64;
    const size_t hbase = (size_t)blockIdx.y * (SS * HD);
    const int x = threadIdx.x & 63, yq = threadIdx.x >> 6;
#pragma unroll
    for (int r = 0; r < 16; r++) {
        const int trow = yq * 16 + r;
        T[trow][x] = V[hbase + (size_t)(t0 + trow) * 64 + x];
    }
    __syncthreads();
#pragma unroll
    for (int r = 0; r < 16; r++) {
        const int drow = yq * 16 + r;
        VT[hbase + (size_t)drow * 1024 + t0 + x] = T[x][drow];
    }
}

// ---------------------------------------------------------------------------
// bf16 MFMA GEMM: C[M=4096, N=1024] = A[M,K=1024] * Bt[N,K]^T + bias.
// 128x128 tile, BK=32, 4 waves in 2x2, per-wave 64x64 (4x4 MFMA 16x16x32).
// MODE 0: bf16 head-split store [(b*16+h)][s][d]. MODE 1: fp32 flat store.
// QKV==1: blockIdx.z in {0,1,2} selects W/bias/out (fused q/k/v launch).
// ---------------------------------------------------------------------------
template <int MODE, int QKV>
__global__ __launch_bounds__(256) void mfma_gemm(
    const u16* __restrict__ A,
    const u16* __restrict__ Bt0, const u16* __restrict__ Bt1, const u16* __restrict__ Bt2,
    const float* __restrict__ bias0, const float* __restrict__ bias1, const float* __restrict__ bias2,
    void* __restrict__ out0, void* __restrict__ out1, void* __restrict__ out2) {
    __shared__ __align__(16) u16 As[128][32];
    __shared__ __align__(16) u16 Bs[128][32];

    const u16* Bt = Bt0;
    const float* bias = bias0;
    void* out = out0;
    if (QKV) {
        const int z = blockIdx.z;
        Bt = (z == 0) ? Bt0 : (z == 1) ? Bt1 : Bt2;
        bias = (z == 0) ? bias0 : (z == 1) ? bias1 : bias2;
        out = (z == 0) ? out0 : (z == 1) ? out1 : out2;
    }

    const int tid = threadIdx.x;
    const int w = tid >> 6, lane = tid & 63, l15 = lane & 15, quad = lane >> 4;
    const int wr = w >> 1, wc = w & 1;
    const int m0 = blockIdx.y * 128, n0 = blockIdx.x * 128;

    f32x4 acc[4][4];
#pragma unroll
    for (int i = 0; i < 4; i++)
#pragma unroll
        for (int j = 0; j < 4; j++) acc[i][j] = (f32x4){0.f, 0.f, 0.f, 0.f};

    for (int k0 = 0; k0 < 1024; k0 += 32) {
#pragma unroll
        for (int i = 0; i < 2; i++) {
            const int c = i * 256 + tid;
            const int row = c >> 2, in4 = c & 3;
            *(uint4*)(&As[row][in4 * 8]) =
                *(const uint4*)(A + (size_t)(m0 + row) * 1024 + k0 + in4 * 8);
            *(uint4*)(&Bs[row][in4 * 8]) =
                *(const uint4*)(Bt + (size_t)(n0 + row) * 1024 + k0 + in4 * 8);
        }
        __syncthreads();
        short8 af[4], bf[4];
#pragma unroll
        for (int i = 0; i < 4; i++)
            af[i] = *(const short8*)(&As[wr * 64 + i * 16 + l15][quad * 8]);
#pragma unroll
        for (int j = 0; j < 4; j++)
            bf[j] = *(const short8*)(&Bs[wc * 64 + j * 16 + l15][quad * 8]);
#pragma unroll
        for (int i = 0; i < 4; i++)
#pragma unroll
            for (int j = 0; j < 4; j++)
                acc[i][j] = __builtin_amdgcn_mfma_f32_16x16x32_bf16(af[i], bf[j], acc[i][j], 0, 0, 0);
        __syncthreads();
    }

#pragma unroll
    for (int i = 0; i < 4; i++) {
#pragma unroll
        for (int j = 0; j < 4; j++) {
            const int nn = n0 + wc * 64 + j * 16 + l15;
            const float bb = bias[nn];
#pragma unroll
            for (int r = 0; r < 4; r++) {
                const int mm = m0 + wr * 64 + i * 16 + quad * 4 + r;
                const float val = acc[i][j][r] + bb;
                if (MODE == 0) {
                    const int b = mm >> 10, s = mm & 1023, h = nn >> 6, d = nn & 63;
                    ((u16*)out)[((size_t)(b * NH + h) * SS + s) * HD + d] = f2bf(val);
                } else {
                    ((float*)out)[(size_t)mm * 1024 + nn] = val;
                }
            }
        }
    }
}

// ---------------------------------------------------------------------------
// Fused attention: per block = one (bh, 64-row q-tile).
// Pass 1: online (m,l) over K-tiles via MFMA QK^T.
// Pass 2: recompute scores, write normalized probs (fp32, the required
// output), LDS round-trip P to A-layout, MFMA PV; store ctx bf16 [B,S,D].
// LDS tiles use k-split layout [ks][row][32] so all frag reads are
// contiguous-1024B ds_read_b128 (conflict-free).
// ---------------------------------------------------------------------------
__global__ __launch_bounds__(256) void attn_fused(
    const u16* __restrict__ Qg, const u16* __restrict__ Kg, const u16* __restrict__ VTg,
    float* __restrict__ probs, u16* __restrict__ ctx) {
    __shared__ __align__(16) u16 Qs[2][64][32];
    __shared__ __align__(16) u16 Ks[2][64][32];
    __shared__ __align__(16) u16 Vs[2][64][32];
    __shared__ __align__(16) u16 Ps[4][2][16][32];

    const int tid = threadIdx.x;
    const int w = tid >> 6, lane = tid & 63, l15 = lane & 15, quad = lane >> 4;
    const int s0 = blockIdx.x * 64;
    const int bh = blockIdx.y;
    const size_t hbase = (size_t)bh * (SS * HD);

    // stage Q tile once
#pragma unroll
    for (int i = 0; i < 2; i++) {
        const int c = i * 256 + tid;
        const int row = c >> 3, ch = c & 7;
        *(uint4*)(&Qs[ch >> 2][row][(ch & 3) * 8]) =
            *(const uint4*)(Qg + hbase + (size_t)(s0 + row) * 64 + ch * 8);
    }

    float m_i[4], l_i[4];
#pragma unroll
    for (int r = 0; r < 4; r++) { m_i[r] = -1e30f; l_i[r] = 0.f; }

    // ---- pass 1: online softmax stats
#pragma unroll 1
    for (int kt = 0; kt < 16; kt++) {
#pragma unroll
        for (int i = 0; i < 2; i++) {
            const int c = i * 256 + tid;
            const int row = c >> 3, ch = c & 7;
            *(uint4*)(&Ks[ch >> 2][row][(ch & 3) * 8]) =
                *(const uint4*)(Kg + hbase + (size_t)(kt * 64 + row) * 64 + ch * 8);
        }
        __syncthreads();
        const short8 aq0 = *(const short8*)(&Qs[0][w * 16 + l15][quad * 8]);
        const short8 aq1 = *(const short8*)(&Qs[1][w * 16 + l15][quad * 8]);
        f32x4 sc[4];
#pragma unroll
        for (int c = 0; c < 4; c++) {
            const short8 bk0 = *(const short8*)(&Ks[0][c * 16 + l15][quad * 8]);
            const short8 bk1 = *(const short8*)(&Ks[1][c * 16 + l15][quad * 8]);
            f32x4 z = {0.f, 0.f, 0.f, 0.f};
            z = __builtin_amdgcn_mfma_f32_16x16x32_bf16(aq0, bk0, z, 0, 0, 0);
            z = __builtin_amdgcn_mfma_f32_16x16x32_bf16(aq1, bk1, z, 0, 0, 0);
            sc[c] = z;
        }
#pragma unroll
        for (int r = 0; r < 4; r++) {
            float v = fmaxf(fmaxf(sc[0][r], sc[1][r]), fmaxf(sc[2][r], sc[3][r])) * 0.125f;
            v = fmaxf(v, __shfl_xor(v, 1));
            v = fmaxf(v, __shfl_xor(v, 2));
            v = fmaxf(v, __shfl_xor(v, 4));
            v = fmaxf(v, __shfl_xor(v, 8));
            const float mn = fmaxf(m_i[r], v);
            float ss = 0.f;
#pragma unroll
            for (int c = 0; c < 4; c++) ss += __expf(sc[c][r] * 0.125f - mn);
            ss += __shfl_xor(ss, 1);
            ss += __shfl_xor(ss, 2);
            ss += __shfl_xor(ss, 4);
            ss += __shfl_xor(ss, 8);
            l_i[r] = l_i[r] * __expf(m_i[r] - mn) + ss;
            m_i[r] = mn;
        }
        __syncthreads();
    }

    float linv[4];
#pragma unroll
    for (int r = 0; r < 4; r++) linv[r] = 1.0f / l_i[r];

    f32x4 oacc[4];
#pragma unroll
    for (int j = 0; j < 4; j++) oacc[j] = (f32x4){0.f, 0.f, 0.f, 0.f};

    // ---- pass 2: recompute scores -> probs write + PV accumulate
#pragma unroll 1
    for (int kt = 0; kt < 16; kt++) {
#pragma unroll
        for (int i = 0; i < 2; i++) {
            const int c = i * 256 + tid;
            const int row = c >> 3, ch = c & 7;
            *(uint4*)(&Ks[ch >> 2][row][(ch & 3) * 8]) =
                *(const uint4*)(Kg + hbase + (size_t)(kt * 64 + row) * 64 + ch * 8);
            *(uint4*)(&Vs[ch >> 2][row][(ch & 3) * 8]) =
                *(const uint4*)(VTg + hbase + (size_t)row * 1024 + kt * 64 + ch * 8);
        }
        __syncthreads();
        const short8 aq0 = *(const short8*)(&Qs[0][w * 16 + l15][quad * 8]);
        const short8 aq1 = *(const short8*)(&Qs[1][w * 16 + l15][quad * 8]);
        f32x4 sc[4];
#pragma unroll
        for (int c = 0; c < 4; c++) {
            const short8 bk0 = *(const short8*)(&Ks[0][c * 16 + l15][quad * 8]);
            const short8 bk1 = *(const short8*)(&Ks[1][c * 16 + l15][quad * 8]);
            f32x4 z = {0.f, 0.f, 0.f, 0.f};
            z = __builtin_amdgcn_mfma_f32_16x16x32_bf16(aq0, bk0, z, 0, 0, 0);
            z = __builtin_amdgcn_mfma_f32_16x16x32_bf16(aq1, bk1, z, 0, 0, 0);
            sc[c] = z;
        }
        const int qrow = s0 + w * 16 + quad * 4;
#pragma unroll
        for (int c = 0; c < 4; c++) {
            const int t = kt * 64 + c * 16 + l15;
#pragma unroll
            for (int r = 0; r < 4; r++) {
                const float p = __expf(sc[c][r] * 0.125f - m_i[r]) * linv[r];
                probs[((size_t)bh * SS + (qrow + r)) * SS + t] = p;
                Ps[w][c >> 1][quad * 4 + r][(c & 1) * 16 + l15] = f2bf(p);
            }
        }
        const short8 ap0 = *(const short8*)(&Ps[w][0][l15][quad * 8]);
        const short8 ap1 = *(const short8*)(&Ps[w][1][l15][quad * 8]);
#pragma unroll
        for (int j = 0; j < 4; j++) {
            const short8 bv0 = *(const short8*)(&Vs[0][j * 16 + l15][quad * 8]);
            const short8 bv1 = *(const short8*)(&Vs[1][j * 16 + l15][quad * 8]);
            oacc[j] = __builtin_amdgcn_mfma_f32_16x16x32_bf16(ap0, bv0, oacc[j], 0, 0, 0);
            oacc[j] = __builtin_amdgcn_mfma_f32_16x16x32_bf16(ap1, bv1, oacc[j], 0, 0, 0);
        }
        __syncthreads();
    }

    // store ctx bf16 [B,S,D]
    const int b = bh >> 4, h = bh & 15;
#pragma unroll
    for (int j = 0; j < 4; j++)
#pragma unroll
        for (int r = 0; r < 4; r++) {
            const int s = s0 + w * 16 + quad * 4 + r;
            ctx[((size_t)b * SS + s) * DD + h * HD + j * 16 + l15] = f2bf(oacc[j][r]);
        }
}

// ---------------------------------------------------------------------------
extern "C" void kernel_launch(void* const* d_in, const int* in_sizes, int n_in,
                              void* d_out, int out_size, void* d_ws, size_t ws_size,
                              hipStream_t stream) {
    const float* x  = (const float*)d_in[0];
    const float* Wq = (const float*)d_in[1];
    const float* bq = (const float*)d_in[2];
    const float* Wk = (const float*)d_in[3];
    const float* bk = (const float*)d_in[4];
    const float* Wv = (const float*)d_in[5];
    const float* bv = (const float*)d_in[6];
    const float* Wo = (const float*)d_in[7];
    const float* bo = (const float*)d_in[8];

    float* out   = (float*)d_out;              // [B,S,D]
    float* probs = out + (size_t)BB * SS * DD; // [B,H,S,S]

    char* ws = (char*)d_ws;
    u16* xb   = (u16*)(ws);                       // 8 MB
    u16* Wtq  = (u16*)(ws + (8ull << 20));        // 2 MB
    u16* Wtk  = (u16*)(ws + (10ull << 20));
    u16* Wtv  = (u16*)(ws + (12ull << 20));
    u16* Wto  = (u16*)(ws + (14ull << 20));
    u16* qb   = (u16*)(ws + (16ull << 20));       // 8 MB each
    u16* kb   = (u16*)(ws + (24ull << 20));
    u16* vb   = (u16*)(ws + (32ull << 20));
    u16* vTb  = (u16*)(ws + (40ull << 20));
    u16* ctxb = (u16*)(ws + (48ull << 20));

    const dim3 blk(256);

    cast_bf16<<<dim3(4096), blk, 0, stream>>>(x, xb);
    transpose_cast_w<<<dim3(16, 16, 4), blk, 0, stream>>>(Wq, Wk, Wv, Wo, Wtq, Wtk, Wtv, Wto);

    // fused q/k/v projections (bf16 head-split out)
    mfma_gemm<0, 1><<<dim3(8, 32, 3), blk, 0, stream>>>(
        xb, Wtq, Wtk, Wtv, bq, bk, bv, qb, kb, vb);

    transpose_v<<<dim3(16, 64), blk, 0, stream>>>(vb, vTb);

    attn_fused<<<dim3(16, 64), blk, 0, stream>>>(qb, kb, vTb, probs, ctxb);

    // out projection (fp32 flat out)
    mfma_gemm<1, 0><<<dim3(8, 32), blk, 0, stream>>>(
        ctxb, Wto, nullptr, nullptr, bo, nullptr, nullptr, out, nullptr, nullptr);
}